// Round 17
// baseline (366.323 us; speedup 1.0000x reference)
//
#include <hip/hip_runtime.h>
#include <hip/hip_bf16.h>
#include <hip/hip_fp16.h>
#include <stdint.h>
#include <stddef.h>

typedef __hip_bfloat16 bf16;
typedef _Float16 f16;
typedef __attribute__((ext_vector_type(8))) short short8;
typedef __attribute__((ext_vector_type(8))) _Float16 half8;
typedef __attribute__((ext_vector_type(4))) float f32x4;
typedef __attribute__((ext_vector_type(2))) float f32x2;
typedef unsigned short us;

__device__ __forceinline__ float dsigm(float z){ return 1.f/(1.f+expf(-z)); }

// DPP sums: quad_perm 0xB1 = xor1, 0x4E = xor2 (within quad)
template<int CTRL>
__device__ __forceinline__ float dpp_term(float x) {
  int xi = __builtin_bit_cast(int, x);
  int yi = __builtin_amdgcn_update_dpp(0, xi, CTRL, 0xF, 0xF, false);
  return __builtin_bit_cast(float, yi);
}
__device__ __forceinline__ float red4(float x) {   // sum over quad (q = lane&3)
  x += dpp_term<0xB1>(x);
  x += dpp_term<0x4E>(x);
  return x;
}

// split fp32 -> hi (rounded bf16) + lo (rounded bf16 residual); scan-side MFMA only
__device__ __forceinline__ void split1(float v, us& h, us& l) {
  bf16 hb = __float2bfloat16(v);
  h = __builtin_bit_cast(us, hb);
  float hf = __bfloat162float(hb);
  bf16 lb = __float2bfloat16(v - hf);
  l = __builtin_bit_cast(us, lb);
}

__device__ __forceinline__ void split8(const float* f, short8& h, short8& l) {
#pragma unroll
  for (int e = 0; e < 8; ++e) {
    us hh, ll;
    split1(f[e], hh, ll);
    h[e] = (short)hh; l[e] = (short)ll;
  }
}

// async global->LDS, 16B per lane (dest = wave-uniform base + lane*16)
__device__ __forceinline__ void gl16(const f16* g, f16* l) {
  __builtin_amdgcn_global_load_lds((const __attribute__((address_space(1))) void*)g,
                                   (__attribute__((address_space(3))) void*)l, 16, 0, 0);
}

//==================== 1. time-shift lerp -> fp16 operands ====================
__device__ __forceinline__ void emit16(const float* __restrict__ marr, int c4,
    const float4& cur, const float4& dlt, f16* __restrict__ out, int row)
{
  float4 m = *(const float4*)(marr + c4);
  f16* o = out + (size_t)row*1024 + c4;
  o[0] = (f16)fmaf(dlt.x, m.x, cur.x);
  o[1] = (f16)fmaf(dlt.y, m.y, cur.y);
  o[2] = (f16)fmaf(dlt.z, m.z, cur.z);
  o[3] = (f16)fmaf(dlt.w, m.w, cur.w);
}

__global__ void k_prep(const float* __restrict__ hs,
    const float* __restrict__ mr, const float* __restrict__ mw, const float* __restrict__ mk,
    const float* __restrict__ mv, const float* __restrict__ ma,
    f16* __restrict__ oxr, f16* __restrict__ oxw, f16* __restrict__ oxk,
    f16* __restrict__ oxv, f16* __restrict__ oxa)
{
  int id = blockIdx.x * 256 + threadIdx.x;
  int row = id >> 8;
  int c4 = (id & 255) << 2;
  int t = row & 2047;
  const float* hp = hs + (size_t)row*1024 + c4;
  float4 cur = *(const float4*)hp;
  float4 prev = make_float4(0.f,0.f,0.f,0.f);
  if (t > 0) prev = *(const float4*)(hp - 1024);
  float4 dlt = make_float4(prev.x-cur.x, prev.y-cur.y, prev.z-cur.z, prev.w-cur.w);
  emit16(mr, c4, cur, dlt, oxr, row);
  emit16(mw, c4, cur, dlt, oxw, row);
  emit16(mk, c4, cur, dlt, oxk, row);
  emit16(mv, c4, cur, dlt, oxv, row);
  emit16(ma, c4, cur, dlt, oxa, row);
}

//==================== 2. weight transpose -> fp16 ====================
struct SrcP { const float* p[10]; };
struct DstP { f16* p[10]; };

__global__ void k_transpose(SrcP S, DstP Dd)
{
  static constexpr int TR[10]  = {1024,1024,1024,1024,1024,  64,1024,  64,1024, 128};
  static constexpr int TCC[10] = {1024,1024,1024,1024,  64,1024,  64,1024, 128,1024};
  static constexpr int TCP[10] = {1024,1024,1024,1024, 128,1024, 128,1024, 128,1024};
  int z = blockIdx.z;
  int R = TR[z], Cc = TCC[z], Cp = TCP[z];
  int n0 = blockIdx.x * 32, r0 = blockIdx.y * 32;
  if (n0 >= Cp || r0 >= R) return;
  const float* src = S.p[z];
  f16* dst = Dd.p[z];
  int tx = threadIdx.x, ty = threadIdx.y;
  __shared__ float tile[32][33];
  if (n0 < Cc) {
#pragma unroll
    for (int i = 0; i < 4; ++i)
      tile[ty + 8*i][tx] = src[(size_t)(r0 + ty + 8*i)*Cc + n0 + tx];
    __syncthreads();
#pragma unroll
    for (int i = 0; i < 4; ++i)
      dst[(size_t)(n0 + ty + 8*i)*R + r0 + tx] = (f16)tile[tx][ty + 8*i];
  } else {
#pragma unroll
    for (int i = 0; i < 4; ++i)
      dst[(size_t)(n0 + ty + 8*i)*R + r0 + tx] = (f16)0.f;
  }
}

//==================== 3. batched fp16 MFMA GEMM (BK=64, XOR-swizzled LDS) ====================
struct GJob {
  const f16* A;              // [4096][lda]
  const f16* Bt;             // [N][ldb]
  float* C;                  // optional fp32 out [4096][ldc]
  f16* Cpk;                  // optional fp16 out [4096][Npk]
  const float* bias;         // optional per-col (added before act)
  int K; int N; int Npk; int ldc; int act;   // act: 0 none, 1 sigmoid, 2 tanh, 3 e^-.5*sigmoid
  int lda; int ldb;
};
struct GJobs { GJob j[5]; };

__global__ __launch_bounds__(256) void k_gemm_fp16(GJobs jobs)
{
  GJob jb = jobs.j[blockIdx.z];
  const int colBase = blockIdx.y * 128;
  if (colBase >= jb.N) return;
  const int rowBase = blockIdx.x * 128;
  __shared__ __align__(16) f16 As[128*64];
  __shared__ __align__(16) f16 Bs[128*64];
  const int tid = threadIdx.x;
  const int l = tid & 63, w = tid >> 6;
  const int wm = w >> 1, wn = w & 1;
  const int lrow = l & 15;
  const int nk = jb.K >> 6;

  const f16* Arow[4]; const f16* Brow[4]; int ld[4];
#pragma unroll
  for (int i2 = 0; i2 < 4; ++i2) {
    int s = (i2*4 + w)*64 + l;
    int ar = s >> 3;
    int unit = s & 7;
    int acs = (unit ^ (ar & 7)) * 8;
    Arow[i2] = jb.A  + (size_t)(rowBase + ar)*jb.lda + acs;
    Brow[i2] = jb.Bt + (size_t)(colBase + ar)*jb.ldb + acs;
    ld[i2] = (i2*4 + w) * 512;
  }

  f32x4 acc[4][4];
#pragma unroll
  for (int i = 0; i < 4; ++i)
#pragma unroll
    for (int j = 0; j < 4; ++j) { f32x4 z = {0.f,0.f,0.f,0.f}; acc[i][j] = z; }

  for (int kt = 0; kt < nk; ++kt) {
    const int kh = kt*64;
#pragma unroll
    for (int i2 = 0; i2 < 4; ++i2) {
      gl16(Arow[i2] + kh, &As[ld[i2]]);
      gl16(Brow[i2] + kh, &Bs[ld[i2]]);
    }
    __syncthreads();
#pragma unroll
    for (int ks = 0; ks < 2; ++ks) {
      half8 ah[4], bh[4];
#pragma unroll
      for (int mt = 0; mt < 4; ++mt) {
        int row = wm*64 + mt*16 + lrow;
        int cu = ks*4 + (l >> 4);
        ah[mt] = *(const half8*)&As[row*64 + ((cu ^ (row & 7)) * 8)];
      }
#pragma unroll
      for (int nt = 0; nt < 4; ++nt) {
        int row = wn*64 + nt*16 + lrow;
        int cu = ks*4 + (l >> 4);
        bh[nt] = *(const half8*)&Bs[row*64 + ((cu ^ (row & 7)) * 8)];
      }
#pragma unroll
      for (int mt = 0; mt < 4; ++mt)
#pragma unroll
        for (int nt = 0; nt < 4; ++nt)
          acc[mt][nt] = __builtin_amdgcn_mfma_f32_16x16x32_f16(ah[mt], bh[nt], acc[mt][nt], 0, 0, 0);
    }
    __syncthreads();
  }
#pragma unroll
  for (int mt = 0; mt < 4; ++mt) {
    int row = rowBase + wm*64 + mt*16 + (l >> 4)*4;
#pragma unroll
    for (int nt = 0; nt < 4; ++nt) {
      int col = colBase + wn*64 + nt*16 + (l & 15);
      float bv = (jb.bias != nullptr) ? jb.bias[col] : 0.f;
#pragma unroll
      for (int rg = 0; rg < 4; ++rg) {
        float v = acc[mt][nt][rg] + bv;
        if (jb.act == 1)      v = dsigm(v);
        else if (jb.act == 2) v = tanhf(v);
        else if (jb.act == 3) v = 0.60653066f * dsigm(v);
        if (jb.C) jb.C[(size_t)(row + rg)*jb.ldc + col] = v;
        if (jb.Cpk && col < jb.Npk)
          jb.Cpk[(size_t)(row + rg)*jb.Npk + col] = (f16)v;
      }
    }
  }
}

//==================== 5. scan prep (fp16 I/O): kk normalize + k update + b=kk*a ====================
__global__ void k_scanprep(f16* __restrict__ kA, f16* __restrict__ aA,
                           const float* __restrict__ kkw, const float* __restrict__ kaw,
                           f16* __restrict__ kkA)
{
  int idx = blockIdx.x * 256 + threadIdx.x;      // 524288 threads, 8 elems each
  size_t gt8 = (size_t)idx * 8;
  int ch = (int)(gt8 & 1023);
  half8 k8 = *(const half8*)(kA + gt8);
  half8 a8 = *(const half8*)(aA + gt8);
  float kw[8], ka_[8];
  *(float4*)&kw[0]  = *(const float4*)(kkw + ch);
  *(float4*)&kw[4]  = *(const float4*)(kkw + ch + 4);
  *(float4*)&ka_[0] = *(const float4*)(kaw + ch);
  *(float4*)&ka_[4] = *(const float4*)(kaw + ch + 4);
  float kkv[8]; float ss = 0.f;
#pragma unroll
  for (int e = 0; e < 8; ++e) { kkv[e] = (float)k8[e] * kw[e]; ss += kkv[e]*kkv[e]; }
  ss += __shfl_xor(ss, 1); ss += __shfl_xor(ss, 2); ss += __shfl_xor(ss, 4);
  float inv = 1.f / fmaxf(sqrtf(ss), 1e-12f);
  half8 kkn8, bb8, kup8;
#pragma unroll
  for (int e = 0; e < 8; ++e) {
    float kkn = kkv[e] * inv;
    float av = (float)a8[e];
    kkn8[e] = (f16)kkn;
    bb8[e]  = (f16)(kkn * av);
    kup8[e] = (f16)((float)k8[e] * fmaf(av - 1.f, ka_[e], 1.f));
  }
  *(half8*)(kkA + gt8) = kkn8;
  *(half8*)(aA + gt8)  = bb8;
  *(half8*)(kA + gt8)  = kup8;
}

//==================== 6a. chunked scan pass 1 (L=32 chunks, 2048 blocks) ====================
// Per (bh, c<64): 32 steps. Thread (i = tid>>2, q = tid&3) owns cols [q*16, q*16+16).
// f16 global operands; staging converts once -> f32 LDS, 4-step groups, double-buffered
// (buffer 1536 floats). Arrays at a*256: 0=ew 1=kk 2=bb 3=k 4=r 5=v.
__device__ __forceinline__ void step_pk16(const float* __restrict__ sb, int s,
    f32x2* u2, f32x2* p2, float* __restrict__ o0A, float* __restrict__ zA,
    size_t base, int i, int q, int j0)
{
  f32x2 kk2[8];
#pragma unroll
  for (int hh = 0; hh < 4; ++hh) {
    float4 a1 = *(const float4*)(sb + 256 + s*64 + j0 + hh*4);
    kk2[hh*2+0] = f32x2{a1.x, a1.y}; kk2[hh*2+1] = f32x2{a1.z, a1.w};
  }
  f32x2 uk2 = u2[0]*kk2[0], pk2 = p2[0]*kk2[0];
#pragma unroll
  for (int e = 1; e < 8; ++e) { uk2 += u2[e]*kk2[e]; pk2 += p2[e]*kk2[e]; }
  float uk = red4(uk2.x + uk2.y);
  float pk = red4(pk2.x + pk2.y);
  float vi = sb[1280 + s*64 + i];
  const f32x2 su2 = {-uk, -uk}, sp2 = {-pk, -pk}, vi2 = {vi, vi};
  f32x2 oo2 = {0.f, 0.f}, zz2 = {0.f, 0.f};
#pragma unroll
  for (int hh = 0; hh < 4; ++hh) {
    float4 e4 = *(const float4*)(sb + 0    + s*64 + j0 + hh*4);
    float4 b4 = *(const float4*)(sb + 512  + s*64 + j0 + hh*4);
    float4 k4 = *(const float4*)(sb + 768  + s*64 + j0 + hh*4);
    float4 r4 = *(const float4*)(sb + 1024 + s*64 + j0 + hh*4);
    f32x2 ew0 = {e4.x, e4.y}, ew1 = {e4.z, e4.w};
    f32x2 bb0 = {b4.x, b4.y}, bb1 = {b4.z, b4.w};
    f32x2 kv0 = {k4.x, k4.y}, kv1 = {k4.z, k4.w};
    f32x2 rr0 = {r4.x, r4.y}, rr1 = {r4.z, r4.w};
    int e0 = hh*2, e1 = hh*2 + 1;
    f32x2 uu0 = u2[e0]*ew0 + su2*bb0 + vi2*kv0;
    u2[e0] = uu0; oo2 += uu0*rr0;
    f32x2 pp0 = p2[e0]*ew0 + sp2*bb0;
    p2[e0] = pp0; zz2 += pp0*rr0;
    f32x2 uu1 = u2[e1]*ew1 + su2*bb1 + vi2*kv1;
    u2[e1] = uu1; oo2 += uu1*rr1;
    f32x2 pp1 = p2[e1]*ew1 + sp2*bb1;
    p2[e1] = pp1; zz2 += pp1*rr1;
  }
  float oo = red4(oo2.x + oo2.y);
  float zz = red4(zz2.x + zz2.y);
  if (q == 0) { o0A[base + i] = oo; zA[base + i] = zz; }
}

__global__ __launch_bounds__(256) void k_scan_p1(
    const f16* __restrict__ rA, const f16* __restrict__ ewA,
    const f16* __restrict__ kA, const f16* __restrict__ vA,
    const f16* __restrict__ kkA, const f16* __restrict__ bbA,
    float* __restrict__ o0A, float* __restrict__ zA,
    float* __restrict__ UcA, float* __restrict__ PTcA)
{
  const int blk = blockIdx.x;                // 32 bh x 64 chunks
  const int bh = blk & 31, c = blk >> 5;
  const int b = bh >> 4, h = bh & 15;
  const int tid = threadIdx.x;
  const int i = tid >> 2, q = tid & 3, j0 = q * 16;
  const size_t base0 = (size_t)b*2048*1024 + (size_t)h*64 + (size_t)(c*32)*1024;

  __shared__ __align__(16) float smem[4160];  // staging 2x1536; [64][65] transpose tail

  // staging: 192 slots of 8 f16 (6 arrays x 4 steps x 8 col-octs)
  const int active = (tid < 192);
  const int a0 = tid >> 5, rm = tid & 31, s0 = rm >> 3, f0 = rm & 7;
  const f16* pa = (a0==0) ? ewA : (a0==1) ? kkA : (a0==2) ? bbA :
                  (a0==3) ? kA  : (a0==4) ? rA  : vA;
  const f16* src0 = pa + base0 + (size_t)s0*1024 + f0*8;
  const int dst0 = a0*256 + s0*64 + f0*8;

  f32x2 u2[8], p2[8];
#pragma unroll
  for (int e = 0; e < 8; ++e) {
    u2[e] = f32x2{0.f, 0.f};
    float p0 = (j0 + 2*e     == i) ? 1.f : 0.f;
    float p1 = (j0 + 2*e + 1 == i) ? 1.f : 0.f;
    p2[e] = f32x2{p0, p1};
  }

  if (active) {
    half8 hh = *(const half8*)(src0);
    *(float4*)&smem[dst0]     = make_float4((float)hh[0], (float)hh[1], (float)hh[2], (float)hh[3]);
    *(float4*)&smem[dst0 + 4] = make_float4((float)hh[4], (float)hh[5], (float)hh[6], (float)hh[7]);
  }
  __syncthreads();

  int curb = 0;
  for (int g = 0; g < 8; ++g) {
    half8 n0;
    if (g < 7 && active) n0 = *(const half8*)(src0 + (size_t)(g+1)*4096);
    const float* sb = smem + curb*1536;
#pragma unroll
    for (int s = 0; s < 4; ++s)
      step_pk16(sb, s, u2, p2, o0A, zA, base0 + (size_t)(g*4 + s)*1024, i, q, j0);
    if (g < 7 && active) {
      int nb = curb ^ 1;
      *(float4*)&smem[nb*1536 + dst0]     = make_float4((float)n0[0], (float)n0[1], (float)n0[2], (float)n0[3]);
      *(float4*)&smem[nb*1536 + dst0 + 4] = make_float4((float)n0[4], (float)n0[5], (float)n0[6], (float)n0[7]);
    }
    __syncthreads();
    curb ^= 1;
  }

  // store U_c (row-major [i][j]) and P_c^T (row-major [j][m]) for pass 2
  const size_t cbase = ((size_t)(bh*64 + c)) * 4096;
#pragma unroll
  for (int e4 = 0; e4 < 4; ++e4)
    *(float4*)(UcA + cbase + (size_t)i*64 + j0 + e4*4) =
      make_float4(u2[e4*2].x, u2[e4*2].y, u2[e4*2+1].x, u2[e4*2+1].y);
  float (*lds)[65] = (float(*)[65])smem;
#pragma unroll
  for (int e = 0; e < 8; ++e) {
    lds[i][j0 + 2*e]     = p2[e].x;
    lds[i][j0 + 2*e + 1] = p2[e].y;
  }
  __syncthreads();
#pragma unroll
  for (int e4 = 0; e4 < 4; ++e4) {
    float4 wv = make_float4(lds[j0 + e4*4 + 0][i], lds[j0 + e4*4 + 1][i],
                            lds[j0 + e4*4 + 2][i], lds[j0 + e4*4 + 3][i]);
    *(float4*)(PTcA + cbase + (size_t)i*64 + j0 + e4*4) = wv;
  }
}

//==================== 6b. chain: S_{c+1} = U_c + S_c @ P_c (64 chunks, split-bf16) ====================
__device__ __forceinline__ void chain_body(int c, int bh, int w, int lr, int lq,
    float (&Slds)[64][65], f32x4 (&acc)[4],
    float (&u_c)[4][4], float4 (&p_c)[2][2],
    float (&u_n)[4][4], float4 (&p_n)[2][2],
    const float* __restrict__ UcA, const float* __restrict__ PTcA,
    float* __restrict__ S0A)
{
  const size_t s0base = ((size_t)bh*64 + c) * 4096;
#pragma unroll
  for (int mt = 0; mt < 4; ++mt)
#pragma unroll
    for (int rg = 0; rg < 4; ++rg) {
      Slds[mt*16 + lq*4 + rg][w*16 + lr] = acc[mt][rg];
      if (c > 0) S0A[s0base + (size_t)(mt*16 + lq*4 + rg)*64 + w*16 + lr] = acc[mt][rg];
    }
  __syncthreads();
  if (c + 1 < 64) {
    const size_t nbase = ((size_t)bh*64 + c + 1) * 4096;
#pragma unroll
    for (int mt = 0; mt < 4; ++mt)
#pragma unroll
      for (int rg = 0; rg < 4; ++rg)
        u_n[mt][rg] = UcA[nbase + (size_t)(mt*16 + lq*4 + rg)*64 + w*16 + lr];
#pragma unroll
    for (int kt = 0; kt < 2; ++kt)
#pragma unroll
      for (int hh = 0; hh < 2; ++hh)
        p_n[kt][hh] = *(const float4*)(PTcA + nbase + (size_t)(w*16 + lr)*64 + kt*32 + lq*8 + hh*4);
  }
  short8 pbh[2], pbl[2];
#pragma unroll
  for (int kt = 0; kt < 2; ++kt) {
    float f[8] = {p_c[kt][0].x, p_c[kt][0].y, p_c[kt][0].z, p_c[kt][0].w,
                  p_c[kt][1].x, p_c[kt][1].y, p_c[kt][1].z, p_c[kt][1].w};
    split8(f, pbh[kt], pbl[kt]);
  }
  f32x4 nacc[4];
#pragma unroll
  for (int mt = 0; mt < 4; ++mt) {
    f32x4 z = {u_c[mt][0], u_c[mt][1], u_c[mt][2], u_c[mt][3]};
    nacc[mt] = z;
  }
#pragma unroll
  for (int kt = 0; kt < 2; ++kt)
#pragma unroll
    for (int mt = 0; mt < 4; ++mt) {
      float f[8];
#pragma unroll
      for (int e = 0; e < 8; ++e) f[e] = Slds[mt*16 + lr][kt*32 + lq*8 + e];
      short8 sah, sal;
      split8(f, sah, sal);
      nacc[mt] = __builtin_amdgcn_mfma_f32_16x16x32_bf16(sah, pbh[kt], nacc[mt], 0, 0, 0);
      nacc[mt] = __builtin_amdgcn_mfma_f32_16x16x32_bf16(sal, pbh[kt], nacc[mt], 0, 0, 0);
      nacc[mt] = __builtin_amdgcn_mfma_f32_16x16x32_bf16(sah, pbl[kt], nacc[mt], 0, 0, 0);
    }
#pragma unroll
  for (int mt = 0; mt < 4; ++mt) acc[mt] = nacc[mt];
  __syncthreads();
}

__global__ __launch_bounds__(256) void k_chain(
    const float* __restrict__ UcA, const float* __restrict__ PTcA,
    float* __restrict__ S0A)
{
  const int bh = blockIdx.x;
  const int l = threadIdx.x & 63, w = threadIdx.x >> 6;
  const int lr = l & 15, lq = l >> 4;
  __shared__ float Slds[64][65];

  f32x4 acc[4];
#pragma unroll
  for (int mt = 0; mt < 4; ++mt) { f32x4 z = {0.f,0.f,0.f,0.f}; acc[mt] = z; }

  float u0[4][4], u1[4][4];
  float4 p0[2][2], p1[2][2];
  {
    const size_t cbase = (size_t)bh * 64 * 4096;
#pragma unroll
    for (int mt = 0; mt < 4; ++mt)
#pragma unroll
      for (int rg = 0; rg < 4; ++rg)
        u0[mt][rg] = UcA[cbase + (size_t)(mt*16 + lq*4 + rg)*64 + w*16 + lr];
#pragma unroll
    for (int kt = 0; kt < 2; ++kt)
#pragma unroll
      for (int hh = 0; hh < 2; ++hh)
        p0[kt][hh] = *(const float4*)(PTcA + cbase + (size_t)(w*16 + lr)*64 + kt*32 + lq*8 + hh*4);
  }
  for (int c = 0; c < 64; c += 2) {
    chain_body(c,     bh, w, lr, lq, Slds, acc, u0, p0, u1, p1, UcA, PTcA, S0A);
    chain_body(c + 1, bh, w, lr, lq, Slds, acc, u1, p1, u0, p0, UcA, PTcA, S0A);
  }
}

//==================== 6c. fused correction + GroupNorm + bonus + gate -> fp16 y ====================
// 1024 blocks = c(0..31)*32 + bh; waves {0,1} correct rows 0-31 with S0[2c],
// waves {2,3} rows 32-63 with S0[2c+1] (L=32 chunks). GN unchanged.
__global__ __launch_bounds__(256) void k_corrpost(
    const float* __restrict__ S0A, const float* __restrict__ zA,
    const float* __restrict__ o0A, const f16* __restrict__ rA,
    const f16* __restrict__ kA, const f16* __restrict__ vA,
    const float* __restrict__ rk, const float* __restrict__ gnw,
    const float* __restrict__ gnb, const f16* __restrict__ gA,
    f16* __restrict__ yH)
{
  const int blk = blockIdx.x;
  const int bh = blk & 31;
  const int c  = blk >> 5;               // 0..31 (64-row block)
  const int b = bh >> 4, h = bh & 15;
  const int l = threadIdx.x & 63, w = threadIdx.x >> 6;
  const int lr = l & 15, lq = l >> 4;
  const int chunk = 2*c + (w >> 1);      // L=32 chunk for this wave's rows

  f32x4 a2[4];
#pragma unroll
  for (int nt = 0; nt < 4; ++nt) { f32x4 z = {0.f,0.f,0.f,0.f}; a2[nt] = z; }

  if (chunk > 0) {
    const size_t s0base = ((size_t)bh*64 + chunk) * 4096;
    short8 sbh[4][2], sbl[4][2];
#pragma unroll
    for (int nt = 0; nt < 4; ++nt)
#pragma unroll
      for (int kt = 0; kt < 2; ++kt) {
        float f[8];
#pragma unroll
        for (int e = 0; e < 8; ++e)
          f[e] = S0A[s0base + (size_t)(nt*16 + lr)*64 + kt*32 + lq*8 + e];
        split8(f, sbh[nt][kt], sbl[nt][kt]);
      }
    short8 zh[2], zl[2];
#pragma unroll
    for (int kt = 0; kt < 2; ++kt) {
      const float* zp = zA + ((size_t)(b*2048 + c*64 + w*16 + lr)*16 + h)*64 + kt*32 + lq*8;
      float f[8];
#pragma unroll
      for (int e = 0; e < 8; ++e) f[e] = zp[e];
      split8(f, zh[kt], zl[kt]);
    }
#pragma unroll
    for (int kt = 0; kt < 2; ++kt)
#pragma unroll
      for (int nt = 0; nt < 4; ++nt) {
        a2[nt] = __builtin_amdgcn_mfma_f32_16x16x32_bf16(zh[kt], sbh[nt][kt], a2[nt], 0, 0, 0);
        a2[nt] = __builtin_amdgcn_mfma_f32_16x16x32_bf16(zl[kt], sbh[nt][kt], a2[nt], 0, 0, 0);
        a2[nt] = __builtin_amdgcn_mfma_f32_16x16x32_bf16(zh[kt], sbl[nt][kt], a2[nt], 0, 0, 0);
      }
  }

#pragma unroll
  for (int rg = 0; rg < 4; ++rg) {
    const int tl = w*16 + lq*4 + rg;
    const size_t trow = (size_t)(b*2048 + c*64 + tl);
    const size_t rb = trow*1024 + h*64;
    float o4[4], v4[4];
    float sum = 0.f, pr = 0.f;
#pragma unroll
    for (int nt = 0; nt < 4; ++nt) {
      const int ii = nt*16 + lr;
      float o = o0A[rb + ii] + a2[nt][rg];
      o4[nt] = o; sum += o;
      v4[nt] = (float)vA[rb + ii];
      pr += (float)rA[rb + ii] * (float)kA[rb + ii] * rk[h*64 + ii];
    }
    sum += __shfl_xor(sum,1); sum += __shfl_xor(sum,2);
    sum += __shfl_xor(sum,4); sum += __shfl_xor(sum,8);
    pr  += __shfl_xor(pr,1);  pr  += __shfl_xor(pr,2);
    pr  += __shfl_xor(pr,4);  pr  += __shfl_xor(pr,8);
    float mean = sum * (1.f/64.f);
    float vp = 0.f;
#pragma unroll
    for (int nt = 0; nt < 4; ++nt) { float d = o4[nt]-mean; vp += d*d; }
    vp += __shfl_xor(vp,1); vp += __shfl_xor(vp,2);
    vp += __shfl_xor(vp,4); vp += __shfl_xor(vp,8);
    float inv = rsqrtf(vp*(1.f/64.f) + 1e-5f);
#pragma unroll
    for (int nt = 0; nt < 4; ++nt) {
      const int ii = nt*16 + lr;
      const int ch = h*64 + ii;
      float y = (o4[nt]-mean)*inv*gnw[ch] + gnb[ch];
      y = fmaf(pr, v4[nt], y);
      y *= (float)gA[rb + ii];
      yH[trow*1024 + ch] = (f16)y;
    }
  }
}

//==================== host ====================
extern "C" void kernel_launch(void* const* d_in, const int* in_sizes, int n_in,
                              void* d_out, int out_size, void* d_ws, size_t ws_size,
                              hipStream_t stream)
{
  (void)in_sizes; (void)n_in; (void)out_size; (void)ws_size;
  const float* hs     = (const float*)d_in[0];
  const float* x_r    = (const float*)d_in[1];
  const float* x_w    = (const float*)d_in[2];
  const float* x_k    = (const float*)d_in[3];
  const float* x_v    = (const float*)d_in[4];
  const float* x_a    = (const float*)d_in[5];
  const float* k_k    = (const float*)d_in[7];
  const float* k_a    = (const float*)d_in[8];
  const float* r_k    = (const float*)d_in[9];
  const float* W_r    = (const float*)d_in[10];
  const float* W_k    = (const float*)d_in[11];
  const float* W_v    = (const float*)d_in[12];
  const float* W_o    = (const float*)d_in[13];
  const float* wla    = (const float*)d_in[14];
  const float* wlb    = (const float*)d_in[15];
  const float* wlbias = (const float*)d_in[16];
  const float* ala    = (const float*)d_in[17];
  const float* alb    = (const float*)d_in[18];
  const float* albias = (const float*)d_in[19];
  const float* gla    = (const float*)d_in[20];
  const float* glb    = (const float*)d_in[21];
  const float* glbias = (const float*)d_in[22];
  const float* gnw    = (const float*)d_in[23];
  const float* gnb    = (const float*)d_in[24];

  char* ws = (char*)d_ws;
  size_t cur = 0;
  auto take = [&](size_t bytes) { size_t o = cur; cur += (bytes + 255) & ~(size_t)255; return o; };

  // fp16 x operands [4096][1024] (8MB each); xw..xa CONSECUTIVE (S0_f spans 32MB)
  f16* xr_h = (f16*)(ws + take((size_t)4096*1024*2));
  f16* xw_h = (f16*)(ws + take((size_t)4096*1024*2));
  f16* xk_h = (f16*)(ws + take((size_t)4096*1024*2));
  f16* xv_h = (f16*)(ws + take((size_t)4096*1024*2));
  f16* xa_h = (f16*)(ws + take((size_t)4096*1024*2));
  // fp16 weights
  f16* Wr_p  = (f16*)(ws + take((size_t)1024*1024*2));
  f16* Wk_p  = (f16*)(ws + take((size_t)1024*1024*2));
  f16* Wv_p  = (f16*)(ws + take((size_t)1024*1024*2));
  f16* Wo_p  = (f16*)(ws + take((size_t)1024*1024*2));
  f16* wla_p = (f16*)(ws + take((size_t)128*1024*2));
  f16* wlb_p = (f16*)(ws + take((size_t)1024*64*2));
  f16* ala_p = (f16*)(ws + take((size_t)128*1024*2));
  f16* alb_p = (f16*)(ws + take((size_t)1024*64*2));
  f16* gla_p = (f16*)(ws + take((size_t)128*1024*2));
  f16* glb_p = (f16*)(ws + take((size_t)1024*128*2));
  // fp16 scan operands
  f16* r_h  = (f16*)(ws + take((size_t)4096*1024*2));
  f16* k_h  = (f16*)(ws + take((size_t)4096*1024*2));
  f16* v_h  = (f16*)(ws + take((size_t)4096*1024*2));
  f16* kk_h = (f16*)(ws + take((size_t)4096*1024*2));
  f16* g_h  = (f16*)(ws + take((size_t)4096*1024*2));
  f16* t2w  = (f16*)(ws + take((size_t)4096*64*2));
  f16* t2a  = (f16*)(ws + take((size_t)4096*64*2));
  f16* t2g  = (f16*)(ws + take((size_t)4096*128*2));
  // fp32 buffers (z 16MB; Uc/PT 32MB each for 64 chunks)
  float* z_f  = (float*)(ws + take((size_t)4096*1024*4));
  float* Uc_f = (float*)(ws + take((size_t)8192*1024*4));
  float* PT_f = (float*)(ws + take((size_t)8192*1024*4));
  // aliases (lifetime-checked against launch order):
  f16*   ew_h = xw_h;            // xw read L2 (w-s1); ew written L3, read p1 L6
  f16*   a_h  = xa_h;            // xa read L2 (a-s1); a written L3, scanprep L5 -> bb, read p1 L6
  f16*   y_h  = xr_h;            // xr read L2 (r); y written L8, read L9
  float* S0_f = (float*)xw_h;    // spans xw+xk+xv+xa (32MB consecutive); all dead after p1 L6;
                                 // S0 written L7, read L8
  float* oF   = (float*)d_out;   // o0 lives in d_out until L9 overwrites

  // L1: prep -> 5 fp16 operands
  k_prep<<<4096, 256, 0, stream>>>(hs, x_r, x_w, x_k, x_v, x_a,
                                   xr_h, xw_h, xk_h, xv_h, xa_h);
  // L1b: weight transpose -> fp16
  SrcP sp; DstP dp;
  sp.p[0]=W_r; sp.p[1]=W_k; sp.p[2]=W_v; sp.p[3]=W_o;
  sp.p[4]=wla; sp.p[5]=wlb; sp.p[6]=ala; sp.p[7]=alb; sp.p[8]=gla; sp.p[9]=glb;
  dp.p[0]=Wr_p; dp.p[1]=Wk_p; dp.p[2]=Wv_p; dp.p[3]=Wo_p;
  dp.p[4]=wla_p; dp.p[5]=wlb_p; dp.p[6]=ala_p; dp.p[7]=alb_p; dp.p[8]=gla_p; dp.p[9]=glb_p;
  k_transpose<<<dim3(32,32,10), dim3(32,8), 0, stream>>>(sp, dp);

  GJobs J{};
  auto job = [](const f16* A, const f16* Bt, float* C, f16* Cpk, const float* bias,
                int K, int N, int Npk, int ldc, int act, int lda, int ldb) {
    GJob j; j.A=A; j.Bt=Bt; j.C=C; j.Cpk=Cpk; j.bias=bias;
    j.K=K; j.N=N; j.Npk=Npk; j.ldc=ldc; j.act=act; j.lda=lda; j.ldb=ldb;
    return j;
  };

  // L2: r, k, v (fp16 outs), w-s1(tanh->t2w), a-s1(->t2a)
  J.j[0] = job(xr_h, Wr_p,  nullptr, r_h, nullptr, 1024, 1024, 1024, 0, 0, 1024, 1024);
  J.j[1] = job(xk_h, Wk_p,  nullptr, k_h, nullptr, 1024, 1024, 1024, 0, 0, 1024, 1024);
  J.j[2] = job(xv_h, Wv_p,  nullptr, v_h, nullptr, 1024, 1024, 1024, 0, 0, 1024, 1024);
  J.j[3] = job(xw_h, wla_p, nullptr, t2w, nullptr, 1024, 128,  64,   0, 2, 1024, 1024);
  J.j[4] = job(xa_h, ala_p, nullptr, t2a, nullptr, 1024, 128,  64,   0, 0, 1024, 1024);
  k_gemm_fp16<<<dim3(32,8,5), 256, 0, stream>>>(J);

  // L3: w-s2 (ew), a-s2 (sigmoid), g-s1 (sigmoid -> t2g)
  J = GJobs{};
  J.j[0] = job(t2w, wlb_p, nullptr, ew_h, wlbias, 64,   1024, 1024, 0, 3, 64,   64);
  J.j[1] = job(t2a, alb_p, nullptr, a_h,  albias, 64,   1024, 1024, 0, 1, 64,   64);
  J.j[2] = job(r_h, gla_p, nullptr, t2g,  nullptr, 1024, 128,  128,  0, 1, 1024, 1024);
  k_gemm_fp16<<<dim3(32,8,3), 256, 0, stream>>>(J);

  // L4: g-s2 (+bias)
  J = GJobs{};
  J.j[0] = job(t2g, glb_p, nullptr, g_h, glbias, 128, 1024, 1024, 0, 0, 128, 128);
  k_gemm_fp16<<<dim3(32,8,1), 256, 0, stream>>>(J);

  // L5: kk normalize + k update + b precompute (fp16 I/O)
  k_scanprep<<<2048, 256, 0, stream>>>(k_h, a_h, k_k, k_a, kk_h);

  // L6-L7: chunked scan (L=32: 2048 p1 blocks, 64-chunk chain)
  k_scan_p1<<<2048, 256, 0, stream>>>(r_h, ew_h, k_h, v_h, kk_h, a_h, oF, z_f, Uc_f, PT_f);
  k_chain<<<32, 256, 0, stream>>>(Uc_f, PT_f, S0_f);

  // L8: fused correction + groupnorm + bonus + gate -> fp16 y
  k_corrpost<<<1024, 256, 0, stream>>>(S0_f, z_f, oF, r_h, k_h, v_h,
                                       r_k, gnw, gnb, g_h, y_h);

  // L9: output projection (overwrites d_out)
  J = GJobs{};
  J.j[0] = job(y_h, Wo_p, (float*)d_out, nullptr, nullptr, 1024, 1024, 0, 1024, 0, 1024, 1024);
  k_gemm_fp16<<<dim3(32,8,1), 256, 0, stream>>>(J);
}

// Round 18
// 315.607 us; speedup vs baseline: 1.1607x; 1.1607x over previous
//
#include <hip/hip_runtime.h>
#include <hip/hip_bf16.h>
#include <hip/hip_fp16.h>
#include <stdint.h>
#include <stddef.h>

typedef __hip_bfloat16 bf16;
typedef _Float16 f16;
typedef __attribute__((ext_vector_type(8))) short short8;
typedef __attribute__((ext_vector_type(8))) _Float16 half8;
typedef __attribute__((ext_vector_type(4))) float f32x4;
typedef __attribute__((ext_vector_type(2))) float f32x2;
typedef unsigned short us;

__device__ __forceinline__ float dsigm(float z){ return 1.f/(1.f+expf(-z)); }

// DPP sums: quad_perm 0xB1 = xor1, 0x4E = xor2 (within quad)
template<int CTRL>
__device__ __forceinline__ float dpp_term(float x) {
  int xi = __builtin_bit_cast(int, x);
  int yi = __builtin_amdgcn_update_dpp(0, xi, CTRL, 0xF, 0xF, false);
  return __builtin_bit_cast(float, yi);
}
__device__ __forceinline__ float red4(float x) {   // sum over quad (q = lane&3)
  x += dpp_term<0xB1>(x);
  x += dpp_term<0x4E>(x);
  return x;
}

// split fp32 -> hi (rounded bf16) + lo (rounded bf16 residual); scan-side MFMA only
__device__ __forceinline__ void split1(float v, us& h, us& l) {
  bf16 hb = __float2bfloat16(v);
  h = __builtin_bit_cast(us, hb);
  float hf = __bfloat162float(hb);
  bf16 lb = __float2bfloat16(v - hf);
  l = __builtin_bit_cast(us, lb);
}

__device__ __forceinline__ void split8(const float* f, short8& h, short8& l) {
#pragma unroll
  for (int e = 0; e < 8; ++e) {
    us hh, ll;
    split1(f[e], hh, ll);
    h[e] = (short)hh; l[e] = (short)ll;
  }
}

// async global->LDS, 16B per lane (dest = wave-uniform base + lane*16)
__device__ __forceinline__ void gl16(const f16* g, f16* l) {
  __builtin_amdgcn_global_load_lds((const __attribute__((address_space(1))) void*)g,
                                   (__attribute__((address_space(3))) void*)l, 16, 0, 0);
}

//==================== 1. time-shift lerp -> fp16 operands ====================
__device__ __forceinline__ void emit16(const float* __restrict__ marr, int c4,
    const float4& cur, const float4& dlt, f16* __restrict__ out, int row)
{
  float4 m = *(const float4*)(marr + c4);
  f16* o = out + (size_t)row*1024 + c4;
  o[0] = (f16)fmaf(dlt.x, m.x, cur.x);
  o[1] = (f16)fmaf(dlt.y, m.y, cur.y);
  o[2] = (f16)fmaf(dlt.z, m.z, cur.z);
  o[3] = (f16)fmaf(dlt.w, m.w, cur.w);
}

__global__ void k_prep(const float* __restrict__ hs,
    const float* __restrict__ mr, const float* __restrict__ mw, const float* __restrict__ mk,
    const float* __restrict__ mv, const float* __restrict__ ma,
    f16* __restrict__ oxr, f16* __restrict__ oxw, f16* __restrict__ oxk,
    f16* __restrict__ oxv, f16* __restrict__ oxa)
{
  int id = blockIdx.x * 256 + threadIdx.x;
  int row = id >> 8;
  int c4 = (id & 255) << 2;
  int t = row & 2047;
  const float* hp = hs + (size_t)row*1024 + c4;
  float4 cur = *(const float4*)hp;
  float4 prev = make_float4(0.f,0.f,0.f,0.f);
  if (t > 0) prev = *(const float4*)(hp - 1024);
  float4 dlt = make_float4(prev.x-cur.x, prev.y-cur.y, prev.z-cur.z, prev.w-cur.w);
  emit16(mr, c4, cur, dlt, oxr, row);
  emit16(mw, c4, cur, dlt, oxw, row);
  emit16(mk, c4, cur, dlt, oxk, row);
  emit16(mv, c4, cur, dlt, oxv, row);
  emit16(ma, c4, cur, dlt, oxa, row);
}

//==================== 2. weight transpose -> fp16 ====================
struct SrcP { const float* p[10]; };
struct DstP { f16* p[10]; };

__global__ void k_transpose(SrcP S, DstP Dd)
{
  static constexpr int TR[10]  = {1024,1024,1024,1024,1024,  64,1024,  64,1024, 128};
  static constexpr int TCC[10] = {1024,1024,1024,1024,  64,1024,  64,1024, 128,1024};
  static constexpr int TCP[10] = {1024,1024,1024,1024, 128,1024, 128,1024, 128,1024};
  int z = blockIdx.z;
  int R = TR[z], Cc = TCC[z], Cp = TCP[z];
  int n0 = blockIdx.x * 32, r0 = blockIdx.y * 32;
  if (n0 >= Cp || r0 >= R) return;
  const float* src = S.p[z];
  f16* dst = Dd.p[z];
  int tx = threadIdx.x, ty = threadIdx.y;
  __shared__ float tile[32][33];
  if (n0 < Cc) {
#pragma unroll
    for (int i = 0; i < 4; ++i)
      tile[ty + 8*i][tx] = src[(size_t)(r0 + ty + 8*i)*Cc + n0 + tx];
    __syncthreads();
#pragma unroll
    for (int i = 0; i < 4; ++i)
      dst[(size_t)(n0 + ty + 8*i)*R + r0 + tx] = (f16)tile[tx][ty + 8*i];
  } else {
#pragma unroll
    for (int i = 0; i < 4; ++i)
      dst[(size_t)(n0 + ty + 8*i)*R + r0 + tx] = (f16)0.f;
  }
}

//==================== 3. batched fp16 MFMA GEMM (BK=64, XOR-swizzled LDS) ====================
struct GJob {
  const f16* A;              // [4096][lda]
  const f16* Bt;             // [N][ldb]
  float* C;                  // optional fp32 out [4096][ldc]
  f16* Cpk;                  // optional fp16 out [4096][Npk]
  const float* bias;         // optional per-col (added before act)
  int K; int N; int Npk; int ldc; int act;   // act: 0 none, 1 sigmoid, 2 tanh, 3 e^-.5*sigmoid
  int lda; int ldb;
};
struct GJobs { GJob j[5]; };

__global__ __launch_bounds__(256) void k_gemm_fp16(GJobs jobs)
{
  GJob jb = jobs.j[blockIdx.z];
  const int colBase = blockIdx.y * 128;
  if (colBase >= jb.N) return;
  const int rowBase = blockIdx.x * 128;
  __shared__ __align__(16) f16 As[128*64];
  __shared__ __align__(16) f16 Bs[128*64];
  const int tid = threadIdx.x;
  const int l = tid & 63, w = tid >> 6;
  const int wm = w >> 1, wn = w & 1;
  const int lrow = l & 15;
  const int nk = jb.K >> 6;

  const f16* Arow[4]; const f16* Brow[4]; int ld[4];
#pragma unroll
  for (int i2 = 0; i2 < 4; ++i2) {
    int s = (i2*4 + w)*64 + l;
    int ar = s >> 3;
    int unit = s & 7;
    int acs = (unit ^ (ar & 7)) * 8;
    Arow[i2] = jb.A  + (size_t)(rowBase + ar)*jb.lda + acs;
    Brow[i2] = jb.Bt + (size_t)(colBase + ar)*jb.ldb + acs;
    ld[i2] = (i2*4 + w) * 512;
  }

  f32x4 acc[4][4];
#pragma unroll
  for (int i = 0; i < 4; ++i)
#pragma unroll
    for (int j = 0; j < 4; ++j) { f32x4 z = {0.f,0.f,0.f,0.f}; acc[i][j] = z; }

  for (int kt = 0; kt < nk; ++kt) {
    const int kh = kt*64;
#pragma unroll
    for (int i2 = 0; i2 < 4; ++i2) {
      gl16(Arow[i2] + kh, &As[ld[i2]]);
      gl16(Brow[i2] + kh, &Bs[ld[i2]]);
    }
    __syncthreads();
#pragma unroll
    for (int ks = 0; ks < 2; ++ks) {
      half8 ah[4], bh[4];
#pragma unroll
      for (int mt = 0; mt < 4; ++mt) {
        int row = wm*64 + mt*16 + lrow;
        int cu = ks*4 + (l >> 4);
        ah[mt] = *(const half8*)&As[row*64 + ((cu ^ (row & 7)) * 8)];
      }
#pragma unroll
      for (int nt = 0; nt < 4; ++nt) {
        int row = wn*64 + nt*16 + lrow;
        int cu = ks*4 + (l >> 4);
        bh[nt] = *(const half8*)&Bs[row*64 + ((cu ^ (row & 7)) * 8)];
      }
#pragma unroll
      for (int mt = 0; mt < 4; ++mt)
#pragma unroll
        for (int nt = 0; nt < 4; ++nt)
          acc[mt][nt] = __builtin_amdgcn_mfma_f32_16x16x32_f16(ah[mt], bh[nt], acc[mt][nt], 0, 0, 0);
    }
    __syncthreads();
  }
#pragma unroll
  for (int mt = 0; mt < 4; ++mt) {
    int row = rowBase + wm*64 + mt*16 + (l >> 4)*4;
#pragma unroll
    for (int nt = 0; nt < 4; ++nt) {
      int col = colBase + wn*64 + nt*16 + (l & 15);
      float bv = (jb.bias != nullptr) ? jb.bias[col] : 0.f;
#pragma unroll
      for (int rg = 0; rg < 4; ++rg) {
        float v = acc[mt][nt][rg] + bv;
        if (jb.act == 1)      v = dsigm(v);
        else if (jb.act == 2) v = tanhf(v);
        else if (jb.act == 3) v = 0.60653066f * dsigm(v);
        if (jb.C) jb.C[(size_t)(row + rg)*jb.ldc + col] = v;
        if (jb.Cpk && col < jb.Npk)
          jb.Cpk[(size_t)(row + rg)*jb.Npk + col] = (f16)v;
      }
    }
  }
}

//==================== 5. scan prep (fp16 I/O): kk normalize + k update + b=kk*a ====================
__global__ void k_scanprep(f16* __restrict__ kA, f16* __restrict__ aA,
                           const float* __restrict__ kkw, const float* __restrict__ kaw,
                           f16* __restrict__ kkA)
{
  int idx = blockIdx.x * 256 + threadIdx.x;      // 524288 threads, 8 elems each
  size_t gt8 = (size_t)idx * 8;
  int ch = (int)(gt8 & 1023);
  half8 k8 = *(const half8*)(kA + gt8);
  half8 a8 = *(const half8*)(aA + gt8);
  float kw[8], ka_[8];
  *(float4*)&kw[0]  = *(const float4*)(kkw + ch);
  *(float4*)&kw[4]  = *(const float4*)(kkw + ch + 4);
  *(float4*)&ka_[0] = *(const float4*)(kaw + ch);
  *(float4*)&ka_[4] = *(const float4*)(kaw + ch + 4);
  float kkv[8]; float ss = 0.f;
#pragma unroll
  for (int e = 0; e < 8; ++e) { kkv[e] = (float)k8[e] * kw[e]; ss += kkv[e]*kkv[e]; }
  ss += __shfl_xor(ss, 1); ss += __shfl_xor(ss, 2); ss += __shfl_xor(ss, 4);
  float inv = 1.f / fmaxf(sqrtf(ss), 1e-12f);
  half8 kkn8, bb8, kup8;
#pragma unroll
  for (int e = 0; e < 8; ++e) {
    float kkn = kkv[e] * inv;
    float av = (float)a8[e];
    kkn8[e] = (f16)kkn;
    bb8[e]  = (f16)(kkn * av);
    kup8[e] = (f16)((float)k8[e] * fmaf(av - 1.f, ka_[e], 1.f));
  }
  *(half8*)(kkA + gt8) = kkn8;
  *(half8*)(aA + gt8)  = bb8;
  *(half8*)(kA + gt8)  = kup8;
}

//==================== 6a. chunked scan pass 1 (256 thr, 16 cols/thread, quad reductions) ====================
// f16 global operands; staging lanes convert once -> f32 LDS [6][8][64] per buffer
// (12KB, double-buffered 24KB). Thread (i = tid>>2, q = tid&3) owns cols [q*16, q*16+16).
// Packed f32x2 math; reductions via 2-stage quad DPP (red4). Arrays: 0=ew 1=kk 2=bb 3=k 4=r 5=v.
__device__ __forceinline__ void step_pk16(const float* __restrict__ sb, int s,
    f32x2* u2, f32x2* p2, float* __restrict__ o0A, float* __restrict__ zA,
    size_t base, int i, int q, int j0)
{
  // dots against kk
  f32x2 kk2[8];
#pragma unroll
  for (int hh = 0; hh < 4; ++hh) {
    float4 a1 = *(const float4*)(sb + 512 + s*64 + j0 + hh*4);
    kk2[hh*2+0] = f32x2{a1.x, a1.y}; kk2[hh*2+1] = f32x2{a1.z, a1.w};
  }
  f32x2 uk2 = u2[0]*kk2[0], pk2 = p2[0]*kk2[0];
#pragma unroll
  for (int e = 1; e < 8; ++e) { uk2 += u2[e]*kk2[e]; pk2 += p2[e]*kk2[e]; }
  float uk = red4(uk2.x + uk2.y);
  float pk = red4(pk2.x + pk2.y);
  float vi = sb[2560 + s*64 + i];
  const f32x2 su2 = {-uk, -uk}, sp2 = {-pk, -pk}, vi2 = {vi, vi};
  f32x2 oo2 = {0.f, 0.f}, zz2 = {0.f, 0.f};
#pragma unroll
  for (int hh = 0; hh < 4; ++hh) {
    float4 e4 = *(const float4*)(sb + 0    + s*64 + j0 + hh*4);
    float4 b4 = *(const float4*)(sb + 1024 + s*64 + j0 + hh*4);
    float4 k4 = *(const float4*)(sb + 1536 + s*64 + j0 + hh*4);
    float4 r4 = *(const float4*)(sb + 2048 + s*64 + j0 + hh*4);
    f32x2 ew0 = {e4.x, e4.y}, ew1 = {e4.z, e4.w};
    f32x2 bb0 = {b4.x, b4.y}, bb1 = {b4.z, b4.w};
    f32x2 kv0 = {k4.x, k4.y}, kv1 = {k4.z, k4.w};
    f32x2 rr0 = {r4.x, r4.y}, rr1 = {r4.z, r4.w};
    int e0 = hh*2, e1 = hh*2 + 1;
    f32x2 uu0 = u2[e0]*ew0 + su2*bb0 + vi2*kv0;
    u2[e0] = uu0; oo2 += uu0*rr0;
    f32x2 pp0 = p2[e0]*ew0 + sp2*bb0;
    p2[e0] = pp0; zz2 += pp0*rr0;
    f32x2 uu1 = u2[e1]*ew1 + su2*bb1 + vi2*kv1;
    u2[e1] = uu1; oo2 += uu1*rr1;
    f32x2 pp1 = p2[e1]*ew1 + sp2*bb1;
    p2[e1] = pp1; zz2 += pp1*rr1;
  }
  float oo = red4(oo2.x + oo2.y);
  float zz = red4(zz2.x + zz2.y);
  if (q == 0) { o0A[base + i] = oo; zA[base + i] = zz; }
}

__global__ __launch_bounds__(256) void k_scan_p1(
    const f16* __restrict__ rA, const f16* __restrict__ ewA,
    const f16* __restrict__ kA, const f16* __restrict__ vA,
    const f16* __restrict__ kkA, const f16* __restrict__ bbA,
    float* __restrict__ o0A, float* __restrict__ zA,
    float* __restrict__ UcA, float* __restrict__ PTcA)
{
  const int blk = blockIdx.x;
  const int bh = blk & 31, c = blk >> 5;
  const int b = bh >> 4, h = bh & 15;
  const int tid = threadIdx.x;
  const int i = tid >> 2, q = tid & 3, j0 = q * 16;
  const size_t base0 = (size_t)b*2048*1024 + (size_t)h*64 + (size_t)(c*64)*1024;

  __shared__ __align__(16) float smem[6144];   // 2x3072 f32 staging; [64][65] tail fits

  // staging: 384 slots of 8 f16; thread covers slot tid (all) and 256+tid (tid<128)
  const int aA_ = tid >> 6, rmA = tid & 63, ssA = rmA >> 3, fA = rmA & 7;
  const f16* paA = (aA_==0) ? ewA : (aA_==1) ? kkA : (aA_==2) ? bbA : kA;
  const f16* srcA = paA + base0 + (size_t)ssA*1024 + fA*8;
  const int dstA = aA_*512 + ssA*64 + fA*8;
  const int hasB = (tid < 128);
  const int sB = 256 + tid;
  const int aB_ = sB >> 6, rmB = sB & 63, ssB = rmB >> 3, fB = rmB & 7;
  const f16* paB = (aB_ == 4) ? rA : vA;
  const f16* srcB = paB + base0 + (size_t)ssB*1024 + fB*8;
  const int dstB = aB_*512 + ssB*64 + fB*8;

  f32x2 u2[8], p2[8];
#pragma unroll
  for (int e = 0; e < 8; ++e) {
    u2[e] = f32x2{0.f, 0.f};
    float p0 = (j0 + 2*e     == i) ? 1.f : 0.f;
    float p1 = (j0 + 2*e + 1 == i) ? 1.f : 0.f;
    p2[e] = f32x2{p0, p1};
  }

  {
    half8 hA = *(const half8*)(srcA);
    *(float4*)&smem[dstA]     = make_float4((float)hA[0], (float)hA[1], (float)hA[2], (float)hA[3]);
    *(float4*)&smem[dstA + 4] = make_float4((float)hA[4], (float)hA[5], (float)hA[6], (float)hA[7]);
    if (hasB) {
      half8 hB = *(const half8*)(srcB);
      *(float4*)&smem[dstB]     = make_float4((float)hB[0], (float)hB[1], (float)hB[2], (float)hB[3]);
      *(float4*)&smem[dstB + 4] = make_float4((float)hB[4], (float)hB[5], (float)hB[6], (float)hB[7]);
    }
  }
  __syncthreads();

  int curb = 0;
  for (int g = 0; g < 8; ++g) {
    half8 nA, nB;
    if (g < 7) {
      nA = *(const half8*)(srcA + (size_t)(g+1)*8192);
      if (hasB) nB = *(const half8*)(srcB + (size_t)(g+1)*8192);
    }
    const float* sb = smem + curb*3072;
#pragma unroll
    for (int s = 0; s < 8; ++s)
      step_pk16(sb, s, u2, p2, o0A, zA, base0 + (size_t)(g*8 + s)*1024, i, q, j0);
    if (g < 7) {
      int nb = curb ^ 1;
      *(float4*)&smem[nb*3072 + dstA]     = make_float4((float)nA[0], (float)nA[1], (float)nA[2], (float)nA[3]);
      *(float4*)&smem[nb*3072 + dstA + 4] = make_float4((float)nA[4], (float)nA[5], (float)nA[6], (float)nA[7]);
      if (hasB) {
        *(float4*)&smem[nb*3072 + dstB]     = make_float4((float)nB[0], (float)nB[1], (float)nB[2], (float)nB[3]);
        *(float4*)&smem[nb*3072 + dstB + 4] = make_float4((float)nB[4], (float)nB[5], (float)nB[6], (float)nB[7]);
      }
    }
    __syncthreads();
    curb ^= 1;
  }

  // store U_c (row-major [i][j]) and P_c^T (row-major [j][m]) for pass 2
  const size_t cbase = ((size_t)(bh*32 + c)) * 4096;
#pragma unroll
  for (int e4 = 0; e4 < 4; ++e4)
    *(float4*)(UcA + cbase + (size_t)i*64 + j0 + e4*4) =
      make_float4(u2[e4*2].x, u2[e4*2].y, u2[e4*2+1].x, u2[e4*2+1].y);
  float (*lds)[65] = (float(*)[65])smem;
#pragma unroll
  for (int e = 0; e < 8; ++e) {
    lds[i][j0 + 2*e]     = p2[e].x;
    lds[i][j0 + 2*e + 1] = p2[e].y;
  }
  __syncthreads();
#pragma unroll
  for (int e4 = 0; e4 < 4; ++e4) {
    float4 wv = make_float4(lds[j0 + e4*4 + 0][i], lds[j0 + e4*4 + 1][i],
                            lds[j0 + e4*4 + 2][i], lds[j0 + e4*4 + 3][i]);
    *(float4*)(PTcA + cbase + (size_t)i*64 + j0 + e4*4) = wv;
  }
}

//==================== 6b. chain: S_{c+1} = U_c + S_c @ P_c (split-bf16, fp32-grade) ====================
__device__ __forceinline__ void chain_body(int c, int bh, int w, int lr, int lq,
    float (&Slds)[64][65], f32x4 (&acc)[4],
    float (&u_c)[4][4], float4 (&p_c)[2][2],
    float (&u_n)[4][4], float4 (&p_n)[2][2],
    const float* __restrict__ UcA, const float* __restrict__ PTcA,
    float* __restrict__ S0A)
{
  const size_t s0base = ((size_t)bh*32 + c) * 4096;
#pragma unroll
  for (int mt = 0; mt < 4; ++mt)
#pragma unroll
    for (int rg = 0; rg < 4; ++rg) {
      Slds[mt*16 + lq*4 + rg][w*16 + lr] = acc[mt][rg];
      if (c > 0) S0A[s0base + (size_t)(mt*16 + lq*4 + rg)*64 + w*16 + lr] = acc[mt][rg];
    }
  __syncthreads();
  if (c + 1 < 32) {
    const size_t nbase = ((size_t)bh*32 + c + 1) * 4096;
#pragma unroll
    for (int mt = 0; mt < 4; ++mt)
#pragma unroll
      for (int rg = 0; rg < 4; ++rg)
        u_n[mt][rg] = UcA[nbase + (size_t)(mt*16 + lq*4 + rg)*64 + w*16 + lr];
#pragma unroll
    for (int kt = 0; kt < 2; ++kt)
#pragma unroll
      for (int hh = 0; hh < 2; ++hh)
        p_n[kt][hh] = *(const float4*)(PTcA + nbase + (size_t)(w*16 + lr)*64 + kt*32 + lq*8 + hh*4);
  }
  short8 pbh[2], pbl[2];
#pragma unroll
  for (int kt = 0; kt < 2; ++kt) {
    float f[8] = {p_c[kt][0].x, p_c[kt][0].y, p_c[kt][0].z, p_c[kt][0].w,
                  p_c[kt][1].x, p_c[kt][1].y, p_c[kt][1].z, p_c[kt][1].w};
    split8(f, pbh[kt], pbl[kt]);
  }
  f32x4 nacc[4];
#pragma unroll
  for (int mt = 0; mt < 4; ++mt) {
    f32x4 z = {u_c[mt][0], u_c[mt][1], u_c[mt][2], u_c[mt][3]};
    nacc[mt] = z;
  }
#pragma unroll
  for (int kt = 0; kt < 2; ++kt)
#pragma unroll
    for (int mt = 0; mt < 4; ++mt) {
      float f[8];
#pragma unroll
      for (int e = 0; e < 8; ++e) f[e] = Slds[mt*16 + lr][kt*32 + lq*8 + e];
      short8 sah, sal;
      split8(f, sah, sal);
      nacc[mt] = __builtin_amdgcn_mfma_f32_16x16x32_bf16(sah, pbh[kt], nacc[mt], 0, 0, 0);
      nacc[mt] = __builtin_amdgcn_mfma_f32_16x16x32_bf16(sal, pbh[kt], nacc[mt], 0, 0, 0);
      nacc[mt] = __builtin_amdgcn_mfma_f32_16x16x32_bf16(sah, pbl[kt], nacc[mt], 0, 0, 0);
    }
#pragma unroll
  for (int mt = 0; mt < 4; ++mt) acc[mt] = nacc[mt];
  __syncthreads();
}

__global__ __launch_bounds__(256) void k_chain(
    const float* __restrict__ UcA, const float* __restrict__ PTcA,
    float* __restrict__ S0A)
{
  const int bh = blockIdx.x;
  const int l = threadIdx.x & 63, w = threadIdx.x >> 6;
  const int lr = l & 15, lq = l >> 4;
  __shared__ float Slds[64][65];

  f32x4 acc[4];
#pragma unroll
  for (int mt = 0; mt < 4; ++mt) { f32x4 z = {0.f,0.f,0.f,0.f}; acc[mt] = z; }

  float u0[4][4], u1[4][4];
  float4 p0[2][2], p1[2][2];
  {
    const size_t cbase = (size_t)bh * 32 * 4096;
#pragma unroll
    for (int mt = 0; mt < 4; ++mt)
#pragma unroll
      for (int rg = 0; rg < 4; ++rg)
        u0[mt][rg] = UcA[cbase + (size_t)(mt*16 + lq*4 + rg)*64 + w*16 + lr];
#pragma unroll
    for (int kt = 0; kt < 2; ++kt)
#pragma unroll
      for (int hh = 0; hh < 2; ++hh)
        p0[kt][hh] = *(const float4*)(PTcA + cbase + (size_t)(w*16 + lr)*64 + kt*32 + lq*8 + hh*4);
  }
  for (int c = 0; c < 32; c += 2) {
    chain_body(c,     bh, w, lr, lq, Slds, acc, u0, p0, u1, p1, UcA, PTcA, S0A);
    chain_body(c + 1, bh, w, lr, lq, Slds, acc, u1, p1, u0, p0, UcA, PTcA, S0A);
  }
}

//==================== 6c. fused correction + GroupNorm + bonus + gate -> fp16 y ====================
__global__ __launch_bounds__(256) void k_corrpost(
    const float* __restrict__ S0A, const float* __restrict__ zA,
    const float* __restrict__ o0A, const f16* __restrict__ rA,
    const f16* __restrict__ kA, const f16* __restrict__ vA,
    const float* __restrict__ rk, const float* __restrict__ gnw,
    const float* __restrict__ gnb, const f16* __restrict__ gA,
    f16* __restrict__ yH)
{
  const int blk = blockIdx.x;
  const int bh = blk & 31;
  const int c  = blk >> 5;               // 0..31
  const int b = bh >> 4, h = bh & 15;
  const int l = threadIdx.x & 63, w = threadIdx.x >> 6;
  const int lr = l & 15, lq = l >> 4;

  f32x4 a2[4];
#pragma unroll
  for (int nt = 0; nt < 4; ++nt) { f32x4 z = {0.f,0.f,0.f,0.f}; a2[nt] = z; }

  if (c > 0) {
    const size_t s0base = ((size_t)bh*32 + c) * 4096;
    short8 sbh[4][2], sbl[4][2];
#pragma unroll
    for (int nt = 0; nt < 4; ++nt)
#pragma unroll
      for (int kt = 0; kt < 2; ++kt) {
        float f[8];
#pragma unroll
        for (int e = 0; e < 8; ++e)
          f[e] = S0A[s0base + (size_t)(nt*16 + lr)*64 + kt*32 + lq*8 + e];
        split8(f, sbh[nt][kt], sbl[nt][kt]);
      }
    short8 zh[2], zl[2];
#pragma unroll
    for (int kt = 0; kt < 2; ++kt) {
      const float* zp = zA + ((size_t)(b*2048 + c*64 + w*16 + lr)*16 + h)*64 + kt*32 + lq*8;
      float f[8];
#pragma unroll
      for (int e = 0; e < 8; ++e) f[e] = zp[e];
      split8(f, zh[kt], zl[kt]);
    }
#pragma unroll
    for (int kt = 0; kt < 2; ++kt)
#pragma unroll
      for (int nt = 0; nt < 4; ++nt) {
        a2[nt] = __builtin_amdgcn_mfma_f32_16x16x32_bf16(zh[kt], sbh[nt][kt], a2[nt], 0, 0, 0);
        a2[nt] = __builtin_amdgcn_mfma_f32_16x16x32_bf16(zl[kt], sbh[nt][kt], a2[nt], 0, 0, 0);
        a2[nt] = __builtin_amdgcn_mfma_f32_16x16x32_bf16(zh[kt], sbl[nt][kt], a2[nt], 0, 0, 0);
      }
  }

#pragma unroll
  for (int rg = 0; rg < 4; ++rg) {
    const int tl = w*16 + lq*4 + rg;
    const size_t trow = (size_t)(b*2048 + c*64 + tl);
    const size_t rb = trow*1024 + h*64;
    float o4[4], v4[4];
    float sum = 0.f, pr = 0.f;
#pragma unroll
    for (int nt = 0; nt < 4; ++nt) {
      const int ii = nt*16 + lr;
      float o = o0A[rb + ii] + a2[nt][rg];
      o4[nt] = o; sum += o;
      v4[nt] = (float)vA[rb + ii];
      pr += (float)rA[rb + ii] * (float)kA[rb + ii] * rk[h*64 + ii];
    }
    sum += __shfl_xor(sum,1); sum += __shfl_xor(sum,2);
    sum += __shfl_xor(sum,4); sum += __shfl_xor(sum,8);
    pr  += __shfl_xor(pr,1);  pr  += __shfl_xor(pr,2);
    pr  += __shfl_xor(pr,4);  pr  += __shfl_xor(pr,8);
    float mean = sum * (1.f/64.f);
    float vp = 0.f;
#pragma unroll
    for (int nt = 0; nt < 4; ++nt) { float d = o4[nt]-mean; vp += d*d; }
    vp += __shfl_xor(vp,1); vp += __shfl_xor(vp,2);
    vp += __shfl_xor(vp,4); vp += __shfl_xor(vp,8);
    float inv = rsqrtf(vp*(1.f/64.f) + 1e-5f);
#pragma unroll
    for (int nt = 0; nt < 4; ++nt) {
      const int ii = nt*16 + lr;
      const int ch = h*64 + ii;
      float y = (o4[nt]-mean)*inv*gnw[ch] + gnb[ch];
      y = fmaf(pr, v4[nt], y);
      y *= (float)gA[rb + ii];
      yH[trow*1024 + ch] = (f16)y;
    }
  }
}

//==================== host ====================
extern "C" void kernel_launch(void* const* d_in, const int* in_sizes, int n_in,
                              void* d_out, int out_size, void* d_ws, size_t ws_size,
                              hipStream_t stream)
{
  (void)in_sizes; (void)n_in; (void)out_size; (void)ws_size;
  const float* hs     = (const float*)d_in[0];
  const float* x_r    = (const float*)d_in[1];
  const float* x_w    = (const float*)d_in[2];
  const float* x_k    = (const float*)d_in[3];
  const float* x_v    = (const float*)d_in[4];
  const float* x_a    = (const float*)d_in[5];
  const float* k_k    = (const float*)d_in[7];
  const float* k_a    = (const float*)d_in[8];
  const float* r_k    = (const float*)d_in[9];
  const float* W_r    = (const float*)d_in[10];
  const float* W_k    = (const float*)d_in[11];
  const float* W_v    = (const float*)d_in[12];
  const float* W_o    = (const float*)d_in[13];
  const float* wla    = (const float*)d_in[14];
  const float* wlb    = (const float*)d_in[15];
  const float* wlbias = (const float*)d_in[16];
  const float* ala    = (const float*)d_in[17];
  const float* alb    = (const float*)d_in[18];
  const float* albias = (const float*)d_in[19];
  const float* gla    = (const float*)d_in[20];
  const float* glb    = (const float*)d_in[21];
  const float* glbias = (const float*)d_in[22];
  const float* gnw    = (const float*)d_in[23];
  const float* gnb    = (const float*)d_in[24];

  char* ws = (char*)d_ws;
  size_t cur = 0;
  auto take = [&](size_t bytes) { size_t o = cur; cur += (bytes + 255) & ~(size_t)255; return o; };

  // fp16 x operands [4096][1024] (8MB each); xk,xv consecutive (S0_f spans them)
  f16* xr_h = (f16*)(ws + take((size_t)4096*1024*2));
  f16* xw_h = (f16*)(ws + take((size_t)4096*1024*2));
  f16* xk_h = (f16*)(ws + take((size_t)4096*1024*2));
  f16* xv_h = (f16*)(ws + take((size_t)4096*1024*2));
  f16* xa_h = (f16*)(ws + take((size_t)4096*1024*2));
  // fp16 weights
  f16* Wr_p  = (f16*)(ws + take((size_t)1024*1024*2));
  f16* Wk_p  = (f16*)(ws + take((size_t)1024*1024*2));
  f16* Wv_p  = (f16*)(ws + take((size_t)1024*1024*2));
  f16* Wo_p  = (f16*)(ws + take((size_t)1024*1024*2));
  f16* wla_p = (f16*)(ws + take((size_t)128*1024*2));
  f16* wlb_p = (f16*)(ws + take((size_t)1024*64*2));
  f16* ala_p = (f16*)(ws + take((size_t)128*1024*2));
  f16* alb_p = (f16*)(ws + take((size_t)1024*64*2));
  f16* gla_p = (f16*)(ws + take((size_t)128*1024*2));
  f16* glb_p = (f16*)(ws + take((size_t)1024*128*2));
  // fp16 scan operands
  f16* r_h  = (f16*)(ws + take((size_t)4096*1024*2));
  f16* k_h  = (f16*)(ws + take((size_t)4096*1024*2));
  f16* v_h  = (f16*)(ws + take((size_t)4096*1024*2));
  f16* kk_h = (f16*)(ws + take((size_t)4096*1024*2));
  f16* g_h  = (f16*)(ws + take((size_t)4096*1024*2));
  f16* t2w  = (f16*)(ws + take((size_t)4096*64*2));
  f16* t2a  = (f16*)(ws + take((size_t)4096*64*2));
  f16* t2g  = (f16*)(ws + take((size_t)4096*128*2));
  // fp32 buffers
  float* z_f  = (float*)(ws + take((size_t)4096*1024*4));
  float* Uc_f = (float*)(ws + take((size_t)4096*1024*4));
  float* PT_f = (float*)(ws + take((size_t)4096*1024*4));
  // aliases (lifetime-checked against launch order):
  f16*   ew_h = xw_h;            // xw read L2 (w-s1); ew written L3, read p1 L6
  f16*   a_h  = xa_h;            // xa read L2 (a-s1); a written L3, scanprep L5 -> bb, read p1 L6
  f16*   y_h  = xr_h;            // xr read L2 (r); y written L8, read L9
  float* S0_f = (float*)xk_h;    // spans xk_h+xv_h (16MB, consecutive); both dead after L2;
                                 // S0 written L7, read L8
  float* oF   = (float*)d_out;   // o0 lives in d_out until L9 overwrites

  // L1: prep -> 5 fp16 operands
  k_prep<<<4096, 256, 0, stream>>>(hs, x_r, x_w, x_k, x_v, x_a,
                                   xr_h, xw_h, xk_h, xv_h, xa_h);
  // L1b: weight transpose -> fp16
  SrcP sp; DstP dp;
  sp.p[0]=W_r; sp.p[1]=W_k; sp.p[2]=W_v; sp.p[3]=W_o;
  sp.p[4]=wla; sp.p[5]=wlb; sp.p[6]=ala; sp.p[7]=alb; sp.p[8]=gla; sp.p[9]=glb;
  dp.p[0]=Wr_p; dp.p[1]=Wk_p; dp.p[2]=Wv_p; dp.p[3]=Wo_p;
  dp.p[4]=wla_p; dp.p[5]=wlb_p; dp.p[6]=ala_p; dp.p[7]=alb_p; dp.p[8]=gla_p; dp.p[9]=glb_p;
  k_transpose<<<dim3(32,32,10), dim3(32,8), 0, stream>>>(sp, dp);

  GJobs J{};
  auto job = [](const f16* A, const f16* Bt, float* C, f16* Cpk, const float* bias,
                int K, int N, int Npk, int ldc, int act, int lda, int ldb) {
    GJob j; j.A=A; j.Bt=Bt; j.C=C; j.Cpk=Cpk; j.bias=bias;
    j.K=K; j.N=N; j.Npk=Npk; j.ldc=ldc; j.act=act; j.lda=lda; j.ldb=ldb;
    return j;
  };

  // L2: r, k, v (fp16 outs), w-s1(tanh->t2w), a-s1(->t2a)
  J.j[0] = job(xr_h, Wr_p,  nullptr, r_h, nullptr, 1024, 1024, 1024, 0, 0, 1024, 1024);
  J.j[1] = job(xk_h, Wk_p,  nullptr, k_h, nullptr, 1024, 1024, 1024, 0, 0, 1024, 1024);
  J.j[2] = job(xv_h, Wv_p,  nullptr, v_h, nullptr, 1024, 1024, 1024, 0, 0, 1024, 1024);
  J.j[3] = job(xw_h, wla_p, nullptr, t2w, nullptr, 1024, 128,  64,   0, 2, 1024, 1024);
  J.j[4] = job(xa_h, ala_p, nullptr, t2a, nullptr, 1024, 128,  64,   0, 0, 1024, 1024);
  k_gemm_fp16<<<dim3(32,8,5), 256, 0, stream>>>(J);

  // L3: w-s2 (ew), a-s2 (sigmoid), g-s1 (sigmoid -> t2g)
  J = GJobs{};
  J.j[0] = job(t2w, wlb_p, nullptr, ew_h, wlbias, 64,   1024, 1024, 0, 3, 64,   64);
  J.j[1] = job(t2a, alb_p, nullptr, a_h,  albias, 64,   1024, 1024, 0, 1, 64,   64);
  J.j[2] = job(r_h, gla_p, nullptr, t2g,  nullptr, 1024, 128,  128,  0, 1, 1024, 1024);
  k_gemm_fp16<<<dim3(32,8,3), 256, 0, stream>>>(J);

  // L4: g-s2 (+bias)
  J = GJobs{};
  J.j[0] = job(t2g, glb_p, nullptr, g_h, glbias, 128, 1024, 1024, 0, 0, 128, 128);
  k_gemm_fp16<<<dim3(32,8,1), 256, 0, stream>>>(J);

  // L5: kk normalize + k update + b precompute (fp16 I/O)
  k_scanprep<<<2048, 256, 0, stream>>>(k_h, a_h, k_k, k_a, kk_h);

  // L6-L7: chunked scan
  k_scan_p1<<<1024, 256, 0, stream>>>(r_h, ew_h, k_h, v_h, kk_h, a_h, oF, z_f, Uc_f, PT_f);
  k_chain<<<32, 256, 0, stream>>>(Uc_f, PT_f, S0_f);

  // L8: fused correction + groupnorm + bonus + gate -> fp16 y
  k_corrpost<<<1024, 256, 0, stream>>>(S0_f, z_f, oF, r_h, k_h, v_h,
                                       r_k, gnw, gnb, g_h, y_h);

  // L9: output projection (overwrites d_out)
  J = GJobs{};
  J.j[0] = job(y_h, Wo_p, (float*)d_out, nullptr, nullptr, 1024, 1024, 0, 1024, 0, 1024, 1024);
  k_gemm_fp16<<<dim3(32,8,1), 256, 0, stream>>>(J);
}